// Round 4
// baseline (703.942 us; speedup 1.0000x reference)
//
#include <hip/hip_runtime.h>

#define NUM_USERS 100000
#define NUM_ITEMS 50000
#define N_NODES   150000   // NUM_USERS + NUM_ITEMS
#define DIM       64
#define BATCH_N   16384
#define NPART     586      // ceil(N_NODES/256)

// ---------------------------------------------------------------------------
// init: x = acc = concat(user_emb, item_emb)   (float4-vectorized copy)
// ---------------------------------------------------------------------------
__global__ __launch_bounds__(256) void lg_init(const float4* __restrict__ user_emb,
                        const float4* __restrict__ item_emb,
                        float4* __restrict__ x,
                        float4* __restrict__ acc) {
    const long user4 = (long)NUM_USERS * DIM / 4;
    const long tot4  = (long)N_NODES  * DIM / 4;
    for (long i = blockIdx.x * (long)blockDim.x + threadIdx.x;
         i < tot4;
         i += (long)gridDim.x * blockDim.x) {
        float4 v = (i < user4) ? user_emb[i] : item_emb[i - user4];
        x[i]   = v;
        acc[i] = v;
    }
}

// ---------------------------------------------------------------------------
// CSR build step 1: histogram of edge rows (int atomics, cnt is L2-resident)
// ---------------------------------------------------------------------------
__global__ __launch_bounds__(256) void lg_hist(const int* __restrict__ rows,
                                               int* __restrict__ cnt, int nnz) {
    int e = blockIdx.x * blockDim.x + threadIdx.x;
    if (e < nnz) atomicAdd(&cnt[rows[e]], 1);
}

// CSR build step 2a: per-block (256-elem) exclusive scan; block totals to part[]
__global__ __launch_bounds__(256) void lg_scan1(const int* __restrict__ cnt,
                                                int* __restrict__ ptr,
                                                int* __restrict__ part) {
    __shared__ int s[256];
    int i = blockIdx.x * 256 + threadIdx.x;
    int v = (i < N_NODES) ? cnt[i] : 0;
    s[threadIdx.x] = v;
    __syncthreads();
    #pragma unroll
    for (int off = 1; off < 256; off <<= 1) {
        int t = (threadIdx.x >= off) ? s[threadIdx.x - off] : 0;
        __syncthreads();
        s[threadIdx.x] += t;
        __syncthreads();
    }
    if (i < N_NODES) ptr[i] = s[threadIdx.x] - v;   // exclusive within block
    if (threadIdx.x == 255) part[blockIdx.x] = s[255];
}

// CSR build step 2b: single-wave exclusive scan of the 586 block totals
__global__ __launch_bounds__(64) void lg_scan2(int* __restrict__ part, int n) {
    int lane = threadIdx.x & 63;
    int run = 0;
    for (int base = 0; base < n; base += 64) {
        int i = base + lane;
        int v = (i < n) ? part[i] : 0;
        int orig = v;
        #pragma unroll
        for (int off = 1; off < 64; off <<= 1) {
            int t = __shfl_up(v, off, 64);
            if (lane >= off) v += t;
        }
        if (i < n) part[i] = run + v - orig;        // exclusive
        run += __shfl(v, 63, 64);
    }
}

// CSR build step 2c: add block offsets; also init cursor = row start
__global__ __launch_bounds__(256) void lg_scan3(int* __restrict__ ptr,
                                                const int* __restrict__ part,
                                                int* __restrict__ cur) {
    int i = blockIdx.x * 256 + threadIdx.x;
    if (i < N_NODES) {
        int p = ptr[i] + part[blockIdx.x];
        ptr[i] = p;
        cur[i] = p;
    }
}

// CSR build step 3: scatter edges into CSR order as interleaved (col,val) pairs
__global__ __launch_bounds__(256) void lg_scatter(const int* __restrict__ rows,
                           const int* __restrict__ cols,
                           const float* __restrict__ vals, int* __restrict__ cur,
                           int2* __restrict__ edges, int nnz) {
    int e = blockIdx.x * blockDim.x + threadIdx.x;
    if (e >= nnz) return;
    int r = rows[e];
    int pos = atomicAdd(&cur[r], 1);
    edges[pos] = make_int2(cols[e], __float_as_int(vals[e]));
}

// ---------------------------------------------------------------------------
// Row-parallel SpMM: one wave per row, lane = dim. No atomics, no shuffles.
// Edge meta (col,val) is a wave-uniform 8B broadcast load (SGPR-based after
// readfirstlane); per edge: 1 uniform load + 1 coalesced 256B gather + 1 FMA.
//   y[r] = sum_e val_e * x[col_e];  acc[r] += y[r]  (fused)
// ---------------------------------------------------------------------------
template <bool WRITE_Y>
__global__ __launch_bounds__(256) void lg_spmm_csr(const int* __restrict__ ptr,
                            const int* __restrict__ cnt,
                            const int2* __restrict__ edges,
                            const float* __restrict__ x, float* __restrict__ y,
                            float* __restrict__ acc) {
    int r    = blockIdx.x * (blockDim.x >> 6) + (threadIdx.x >> 6);
    int lane = threadIdx.x & 63;
    if (r >= N_NODES) return;
    int start = __builtin_amdgcn_readfirstlane(ptr[r]);   // SGPR: scalar addressing
    int len   = __builtin_amdgcn_readfirstlane(cnt[r]);
    const int2* __restrict__ ep = edges + start;
    float s0 = 0.0f, s1 = 0.0f;
    int j = 0;
    for (; j + 2 <= len; j += 2) {          // 2 accumulators break the FMA chain
        int2 e0 = ep[j];
        int2 e1 = ep[j + 1];
        s0 += __int_as_float(e0.y) * x[(long)e0.x * DIM + lane];
        s1 += __int_as_float(e1.y) * x[(long)e1.x * DIM + lane];
    }
    if (j < len) {
        int2 e0 = ep[j];
        s0 += __int_as_float(e0.y) * x[(long)e0.x * DIM + lane];
    }
    float sum = s0 + s1;
    long o = (long)r * DIM + lane;
    if (WRITE_Y) y[o] = sum;
    acc[o] += sum;
}

// ---------------------------------------------------------------------------
// preds[b] = dot(acc[u], acc[NUM_USERS+i]) / 16 — one wave per batch element
// ---------------------------------------------------------------------------
__global__ __launch_bounds__(256) void lg_dot(const float* __restrict__ acc,
                       const int*   __restrict__ uidx,
                       const int*   __restrict__ iidx,
                       float*       __restrict__ out,
                       int batch) {
    int b    = blockIdx.x * (blockDim.x >> 6) + (threadIdx.x >> 6);
    int lane = threadIdx.x & 63;
    if (b >= batch) return;
    long u = (long)uidx[b];
    long t = (long)NUM_USERS + iidx[b];
    float p = acc[u * DIM + lane] * acc[t * DIM + lane] * (1.0f / 16.0f);
    #pragma unroll
    for (int off = 32; off > 0; off >>= 1)
        p += __shfl_down(p, off, 64);
    if (lane == 0) out[b] = p;
}

// ---------------------------------------------------------------------------
extern "C" void kernel_launch(void* const* d_in, const int* in_sizes, int n_in,
                              void* d_out, int out_size, void* d_ws, size_t ws_size,
                              hipStream_t stream) {
    const float* user_emb  = (const float*)d_in[0];
    const float* item_emb  = (const float*)d_in[1];
    const int*   edge_rows = (const int*)  d_in[2];
    const int*   edge_cols = (const int*)  d_in[3];
    const float* edge_vals = (const float*)d_in[4];
    const int*   user_inp  = (const int*)  d_in[5];
    const int*   item_inp  = (const int*)  d_in[6];
    float*       out       = (float*)d_out;

    const int nnz = in_sizes[2];

    const size_t embBytes = (size_t)N_NODES * DIM * sizeof(float);  // 38.4 MB
    const size_t nodeInts = (size_t)N_NODES * sizeof(int);          // 600 KB
    const size_t need = 3 * embBytes + (size_t)nnz * 8 + 3 * nodeInts
                      + (size_t)NPART * sizeof(int);
    if (ws_size < need) return;  // workspace too small: fail clean (no OOB writes)

    char* ws = (char*)d_ws;
    float* x     = (float*)(ws);
    float* y     = (float*)(ws + embBytes);
    float* acc   = (float*)(ws + 2 * embBytes);
    int2*  edges = (int2*) (ws + 3 * embBytes);
    int*   cnt   = (int*)  (ws + 3 * embBytes + (size_t)nnz * 8);
    int*   ptr   = (int*)  (ws + 3 * embBytes + (size_t)nnz * 8 + nodeInts);
    int*   cur   = (int*)  (ws + 3 * embBytes + (size_t)nnz * 8 + 2 * nodeInts);
    int*   part  = (int*)  (ws + 3 * embBytes + (size_t)nnz * 8 + 3 * nodeInts);

    // --- init embeddings (x = acc = concat) ---
    lg_init<<<2048, 256, 0, stream>>>((const float4*)user_emb,
                                      (const float4*)item_emb,
                                      (float4*)x, (float4*)acc);

    // --- CSR build (once; shared by all 3 layers) ---
    hipMemsetAsync(cnt, 0, nodeInts, stream);
    const int eb = (nnz + 255) / 256;
    lg_hist   <<<eb,    256, 0, stream>>>(edge_rows, cnt, nnz);
    lg_scan1  <<<NPART, 256, 0, stream>>>(cnt, ptr, part);
    lg_scan2  <<<1,      64, 0, stream>>>(part, NPART);
    lg_scan3  <<<NPART, 256, 0, stream>>>(ptr, part, cur);
    lg_scatter<<<eb,    256, 0, stream>>>(edge_rows, edge_cols, edge_vals,
                                          cur, edges, nnz);

    // --- 3 propagation layers, acc-update fused; last layer skips y write ---
    const int rowBlocks = (N_NODES + 3) / 4;   // 4 waves (rows) per 256-thr block
    lg_spmm_csr<true ><<<rowBlocks, 256, 0, stream>>>(ptr, cnt, edges, x, y, acc);
    lg_spmm_csr<true ><<<rowBlocks, 256, 0, stream>>>(ptr, cnt, edges, y, x, acc);
    lg_spmm_csr<false><<<rowBlocks, 256, 0, stream>>>(ptr, cnt, edges, x, y, acc);

    // --- final batched dot ---
    lg_dot<<<(BATCH_N + 3) / 4, 256, 0, stream>>>(acc, user_inp, item_inp,
                                                  out, BATCH_N);
}

// Round 6
// 666.329 us; speedup vs baseline: 1.0564x; 1.0564x over previous
//
#include <hip/hip_runtime.h>

#define NUM_USERS 100000
#define NUM_ITEMS 50000
#define N_NODES   150000   // NUM_USERS + NUM_ITEMS
#define DIM       64
#define BATCH_N   16384
#define NPART     586      // ceil(N_NODES/256)
#define SC_PASSES 8        // scatter row-slice passes (L2-resident dest window)
#define SC_SLICE  18750    // ceil(N_NODES/SC_PASSES)

// ---------------------------------------------------------------------------
// init: x = acc = concat(user_emb, item_emb)   (float4-vectorized copy)
// ---------------------------------------------------------------------------
__global__ __launch_bounds__(256) void lg_init(const float4* __restrict__ user_emb,
                        const float4* __restrict__ item_emb,
                        float4* __restrict__ x,
                        float4* __restrict__ acc) {
    const long user4 = (long)NUM_USERS * DIM / 4;
    const long tot4  = (long)N_NODES  * DIM / 4;
    for (long i = blockIdx.x * (long)blockDim.x + threadIdx.x;
         i < tot4;
         i += (long)gridDim.x * blockDim.x) {
        float4 v = (i < user4) ? user_emb[i] : item_emb[i - user4];
        x[i]   = v;
        acc[i] = v;
    }
}

// ---------------------------------------------------------------------------
// CSR build step 1: histogram of edge rows (int atomics, cnt is L2-resident)
// ---------------------------------------------------------------------------
__global__ __launch_bounds__(256) void lg_hist(const int* __restrict__ rows,
                                               int* __restrict__ cnt, int nnz) {
    int e = blockIdx.x * blockDim.x + threadIdx.x;
    if (e < nnz) atomicAdd(&cnt[rows[e]], 1);
}

// CSR build step 2a: per-block (256-elem) exclusive scan; block totals to part[]
__global__ __launch_bounds__(256) void lg_scan1(const int* __restrict__ cnt,
                                                int* __restrict__ ptr,
                                                int* __restrict__ part) {
    __shared__ int s[256];
    int i = blockIdx.x * 256 + threadIdx.x;
    int v = (i < N_NODES) ? cnt[i] : 0;
    s[threadIdx.x] = v;
    __syncthreads();
    #pragma unroll
    for (int off = 1; off < 256; off <<= 1) {
        int t = (threadIdx.x >= off) ? s[threadIdx.x - off] : 0;
        __syncthreads();
        s[threadIdx.x] += t;
        __syncthreads();
    }
    if (i < N_NODES) ptr[i] = s[threadIdx.x] - v;   // exclusive within block
    if (threadIdx.x == 255) part[blockIdx.x] = s[255];
}

// CSR build step 2b: single-wave exclusive scan of the 586 block totals
__global__ __launch_bounds__(64) void lg_scan2(int* __restrict__ part, int n) {
    int lane = threadIdx.x & 63;
    int run = 0;
    for (int base = 0; base < n; base += 64) {
        int i = base + lane;
        int v = (i < n) ? part[i] : 0;
        int orig = v;
        #pragma unroll
        for (int off = 1; off < 64; off <<= 1) {
            int t = __shfl_up(v, off, 64);
            if (lane >= off) v += t;
        }
        if (i < n) part[i] = run + v - orig;        // exclusive
        run += __shfl(v, 63, 64);
    }
}

// CSR build step 2c: add block offsets; also init cursor = row start
__global__ __launch_bounds__(256) void lg_scan3(int* __restrict__ ptr,
                                                const int* __restrict__ part,
                                                int* __restrict__ cur) {
    int i = blockIdx.x * 256 + threadIdx.x;
    if (i < N_NODES) {
        int p = ptr[i] + part[blockIdx.x];
        ptr[i] = p;
        cur[i] = p;
    }
}

// ---------------------------------------------------------------------------
// CSR build step 3: scatter edges into CSR order as interleaved (col,val).
// Row-sliced into SC_PASSES passes: each pass's destination window is a
// contiguous ~2.4 MB range (CSR order!), so the random 8B RMWs stay L2-
// resident and each dirty line is written back once. Kills the 149 MB
// write amplification measured in round 4 (2.4M x 64B line per 8B write).
// ---------------------------------------------------------------------------
__global__ __launch_bounds__(256) void lg_scatter_pass(const int* __restrict__ rows,
                           const int* __restrict__ cols,
                           const float* __restrict__ vals, int* __restrict__ cur,
                           int2* __restrict__ edges, int nnz, int lo, int hi) {
    int e = blockIdx.x * blockDim.x + threadIdx.x;
    if (e >= nnz) return;
    int r = rows[e];
    if (r < lo || r >= hi) return;     // 7/8 of lanes exit: cheap row-slice filter
    int pos = atomicAdd(&cur[r], 1);
    edges[pos] = make_int2(cols[e], __float_as_int(vals[e]));
}

// ---------------------------------------------------------------------------
// Row-parallel SpMM: one wave per row, lane = dim. No atomics, no shuffles.
// Edge meta (col,val) is a wave-uniform 8B broadcast load (SGPR-based after
// readfirstlane); per edge: 1 uniform load + 1 coalesced 256B gather + 1 FMA.
// 4 accumulators for ILP. 32-bit gather indexing ((c<<6)+lane < 2^24).
//   y[r] = sum_e val_e * x[col_e];  acc[r] += y[r]  (fused)
// ---------------------------------------------------------------------------
template <bool WRITE_Y>
__global__ __launch_bounds__(256) void lg_spmm_csr(const int* __restrict__ ptr,
                            const int* __restrict__ cnt,
                            const int2* __restrict__ edges,
                            const float* __restrict__ x, float* __restrict__ y,
                            float* __restrict__ acc) {
    int r    = blockIdx.x * (blockDim.x >> 6) + (threadIdx.x >> 6);
    int lane = threadIdx.x & 63;
    if (r >= N_NODES) return;
    int start = __builtin_amdgcn_readfirstlane(ptr[r]);   // SGPR: scalar addressing
    int len   = __builtin_amdgcn_readfirstlane(cnt[r]);
    const int2* __restrict__ ep = edges + start;
    float s0 = 0.0f, s1 = 0.0f, s2 = 0.0f, s3 = 0.0f;
    int j = 0;
    for (; j + 4 <= len; j += 4) {      // 4 accumulators break the FMA chain
        int2 e0 = ep[j];
        int2 e1 = ep[j + 1];
        int2 e2 = ep[j + 2];
        int2 e3 = ep[j + 3];
        s0 += __int_as_float(e0.y) * x[(e0.x << 6) + lane];
        s1 += __int_as_float(e1.y) * x[(e1.x << 6) + lane];
        s2 += __int_as_float(e2.y) * x[(e2.x << 6) + lane];
        s3 += __int_as_float(e3.y) * x[(e3.x << 6) + lane];
    }
    for (; j < len; ++j) {
        int2 e0 = ep[j];
        s0 += __int_as_float(e0.y) * x[(e0.x << 6) + lane];
    }
    float sum = (s0 + s1) + (s2 + s3);
    int o = (r << 6) + lane;
    if (WRITE_Y) y[o] = sum;
    acc[o] += sum;
}

// ---------------------------------------------------------------------------
// preds[b] = dot(acc[u], acc[NUM_USERS+i]) / 16 — one wave per batch element
// ---------------------------------------------------------------------------
__global__ __launch_bounds__(256) void lg_dot(const float* __restrict__ acc,
                       const int*   __restrict__ uidx,
                       const int*   __restrict__ iidx,
                       float*       __restrict__ out,
                       int batch) {
    int b    = blockIdx.x * (blockDim.x >> 6) + (threadIdx.x >> 6);
    int lane = threadIdx.x & 63;
    if (b >= batch) return;
    int u = uidx[b];
    int t = NUM_USERS + iidx[b];
    float p = acc[(u << 6) + lane] * acc[(t << 6) + lane] * (1.0f / 16.0f);
    #pragma unroll
    for (int off = 32; off > 0; off >>= 1)
        p += __shfl_down(p, off, 64);
    if (lane == 0) out[b] = p;
}

// ---------------------------------------------------------------------------
extern "C" void kernel_launch(void* const* d_in, const int* in_sizes, int n_in,
                              void* d_out, int out_size, void* d_ws, size_t ws_size,
                              hipStream_t stream) {
    const float* user_emb  = (const float*)d_in[0];
    const float* item_emb  = (const float*)d_in[1];
    const int*   edge_rows = (const int*)  d_in[2];
    const int*   edge_cols = (const int*)  d_in[3];
    const float* edge_vals = (const float*)d_in[4];
    const int*   user_inp  = (const int*)  d_in[5];
    const int*   item_inp  = (const int*)  d_in[6];
    float*       out       = (float*)d_out;

    const int nnz = in_sizes[2];

    const size_t embBytes = (size_t)N_NODES * DIM * sizeof(float);  // 38.4 MB
    const size_t nodeInts = (size_t)N_NODES * sizeof(int);          // 600 KB
    const size_t need = 3 * embBytes + (size_t)nnz * 8 + 3 * nodeInts
                      + (size_t)NPART * sizeof(int);
    if (ws_size < need) return;  // workspace too small: fail clean (no OOB writes)

    char* ws = (char*)d_ws;
    float* x     = (float*)(ws);
    float* y     = (float*)(ws + embBytes);
    float* acc   = (float*)(ws + 2 * embBytes);
    int2*  edges = (int2*) (ws + 3 * embBytes);
    int*   cnt   = (int*)  (ws + 3 * embBytes + (size_t)nnz * 8);
    int*   ptr   = (int*)  (ws + 3 * embBytes + (size_t)nnz * 8 + nodeInts);
    int*   cur   = (int*)  (ws + 3 * embBytes + (size_t)nnz * 8 + 2 * nodeInts);
    int*   part  = (int*)  (ws + 3 * embBytes + (size_t)nnz * 8 + 3 * nodeInts);

    // --- init embeddings (x = acc = concat) ---
    lg_init<<<2048, 256, 0, stream>>>((const float4*)user_emb,
                                      (const float4*)item_emb,
                                      (float4*)x, (float4*)acc);

    // --- CSR build (once; shared by all 3 layers) ---
    hipMemsetAsync(cnt, 0, nodeInts, stream);
    const int eb = (nnz + 255) / 256;
    lg_hist <<<eb,    256, 0, stream>>>(edge_rows, cnt, nnz);
    lg_scan1<<<NPART, 256, 0, stream>>>(cnt, ptr, part);
    lg_scan2<<<1,      64, 0, stream>>>(part, NPART);
    lg_scan3<<<NPART, 256, 0, stream>>>(ptr, part, cur);
    for (int p = 0; p < SC_PASSES; ++p) {
        lg_scatter_pass<<<eb, 256, 0, stream>>>(edge_rows, edge_cols, edge_vals,
                                                cur, edges, nnz,
                                                p * SC_SLICE, (p + 1) * SC_SLICE);
    }

    // --- 3 propagation layers, acc-update fused; last layer skips y write ---
    const int rowBlocks = (N_NODES + 3) / 4;   // 4 waves (rows) per 256-thr block
    lg_spmm_csr<true ><<<rowBlocks, 256, 0, stream>>>(ptr, cnt, edges, x, y, acc);
    lg_spmm_csr<true ><<<rowBlocks, 256, 0, stream>>>(ptr, cnt, edges, y, x, acc);
    lg_spmm_csr<false><<<rowBlocks, 256, 0, stream>>>(ptr, cnt, edges, x, y, acc);

    // --- final batched dot ---
    lg_dot<<<(BATCH_N + 3) / 4, 256, 0, stream>>>(acc, user_inp, item_inp,
                                                  out, BATCH_N);
}